// Round 1
// baseline (515.116 us; speedup 1.0000x reference)
//
#include <hip/hip_runtime.h>
#include <math.h>

#define NN 100000
#define NE 1600000
#define DD 64

// ---------------- zero the hi accumulator in workspace ----------------
__global__ __launch_bounds__(256) void zero_ws(float4* __restrict__ p, int n4) {
    int i = blockIdx.x * blockDim.x + threadIdx.x;
    const int stride = gridDim.x * blockDim.x;
    for (; i < n4; i += stride) p[i] = make_float4(0.f, 0.f, 0.f, 0.f);
}

// ---------------- edge scatter: hi[dst] += x[src] * w ----------------
// one wave (64 lanes) per edge; lane = feature dim -> 256B coalesced
// gather + 256B of fp32 atomics per edge.
__global__ __launch_bounds__(256) void scatter_edges(
        const float* __restrict__ x,
        const int*   __restrict__ esrc,
        const int*   __restrict__ edst,
        const float* __restrict__ ew,
        float*       __restrict__ hi) {
    const int lane   = threadIdx.x & 63;
    int       wave   = (blockIdx.x * blockDim.x + threadIdx.x) >> 6;
    const int nwaves = (gridDim.x * blockDim.x) >> 6;
    for (int e = wave; e < NE; e += nwaves) {
        const int   s = esrc[e];
        const int   d = edst[e];
        const float w = ew[e];
        const float v = x[s * DD + lane] * w;
        atomicAdd(&hi[d * DD + lane], v);
    }
}

// ---------------- fused epilogue ----------------
// support = 0.9*hi + 0.1*h0 ; out = theta*(support@W) + (1-theta)*support + x
// one wave per row; lane j keeps column j of W in 64 VGPRs (loaded once per
// wave), support row broadcast via __shfl.
__global__ __launch_bounds__(256) void fused_epilogue(
        const float* __restrict__ hi,
        const float* __restrict__ h0,
        const float* __restrict__ x,
        const float* __restrict__ W,
        const int*   __restrict__ lp,
        float*       __restrict__ out) {
    const int lane   = threadIdx.x & 63;
    int       wave   = (blockIdx.x * blockDim.x + threadIdx.x) >> 6;
    const int nwaves = (gridDim.x * blockDim.x) >> 6;

    const float theta = logf(0.5f / (float)lp[0] + 1.0f);
    const float omt   = 1.0f - theta;

    // column `lane` of W: W[k][lane], k = 0..63 (coalesced across lanes)
    float wcol[64];
#pragma unroll
    for (int k = 0; k < 64; ++k) wcol[k] = W[k * DD + lane];

    for (int row = wave; row < NN; row += nwaves) {
        const float sv = 0.9f * hi[row * DD + lane] + 0.1f * h0[row * DD + lane];
        float acc = 0.f;
#pragma unroll
        for (int k = 0; k < 64; ++k)
            acc = fmaf(__shfl(sv, k, 64), wcol[k], acc);
        out[row * DD + lane] = fmaf(theta, acc, omt * sv) + x[row * DD + lane];
    }
}

extern "C" void kernel_launch(void* const* d_in, const int* in_sizes, int n_in,
                              void* d_out, int out_size, void* d_ws, size_t ws_size,
                              hipStream_t stream) {
    const float* x    = (const float*)d_in[0];   // [NN, 64]
    const float* h0   = (const float*)d_in[1];   // [NN, 64]
    const int*   esrc = (const int*)  d_in[2];   // [NE]
    const int*   edst = (const int*)  d_in[3];   // [NE]
    const float* ew   = (const float*)d_in[4];   // [NE]
    const float* W    = (const float*)d_in[5];   // [64, 64]
    const int*   lp   = (const int*)  d_in[6];   // scalar l
    float*       out  = (float*)d_out;
    float*       hi   = (float*)d_ws;            // [NN, 64] accumulator

    // 1) zero hi (ws is poisoned 0xAA before every timed call)
    zero_ws<<<2048, 256, 0, stream>>>((float4*)hi, NN * DD / 4);

    // 2) edge scatter
    scatter_edges<<<4096, 256, 0, stream>>>(x, esrc, edst, ew, hi);

    // 3) fused epilogue
    fused_epilogue<<<2048, 256, 0, stream>>>(hi, h0, x, W, lp, out);
}

// Round 3
// 499.540 us; speedup vs baseline: 1.0312x; 1.0312x over previous
//
#include <hip/hip_runtime.h>
#include <math.h>

#define NN 100000
#define NE 1600000
#define DD 64

#define SCAN_B 1024
#define SCAN_NB ((NN + SCAN_B - 1) / SCAN_B)   // 98 blocks

// ---------------- zero the per-dst counts ----------------
__global__ __launch_bounds__(256) void zero_cnt(int* __restrict__ cnt) {
    int i = blockIdx.x * blockDim.x + threadIdx.x;
    if (i < NN) cnt[i] = 0;
}

// ---------------- histogram of dst degrees ----------------
__global__ __launch_bounds__(256) void hist(const int* __restrict__ edst,
                                            int* __restrict__ cnt) {
    int i = blockIdx.x * blockDim.x + threadIdx.x;
    const int stride = gridDim.x * blockDim.x;
    for (int e = i; e < NE; e += stride) atomicAdd(&cnt[edst[e]], 1);
}

// ---------------- scan step 1: per-block sums ----------------
__global__ __launch_bounds__(SCAN_B) void scan1(const int* __restrict__ cnt,
                                                int* __restrict__ partial) {
    int i = blockIdx.x * SCAN_B + threadIdx.x;
    int v = (i < NN) ? cnt[i] : 0;
#pragma unroll
    for (int o = 1; o < 64; o <<= 1) v += __shfl_xor(v, o, 64);
    __shared__ int wsum[SCAN_B / 64];
    const int wid = threadIdx.x >> 6, lane = threadIdx.x & 63;
    if (lane == 0) wsum[wid] = v;
    __syncthreads();
    if (threadIdx.x == 0) {
        int s = 0;
#pragma unroll
        for (int w = 0; w < SCAN_B / 64; ++w) s += wsum[w];
        partial[blockIdx.x] = s;
    }
}

// ---------------- scan step 2: exclusive scan of partials ----------------
__global__ void scan2(int* __restrict__ partial) {
    if (threadIdx.x == 0) {
        int run = 0;
        for (int b = 0; b < SCAN_NB; ++b) {
            int t = partial[b];
            partial[b] = run;
            run += t;
        }
    }
}

// ---------------- scan step 3: exclusive offsets + cursor copy ----------------
__global__ __launch_bounds__(SCAN_B) void scan3(const int* __restrict__ cnt,
                                                const int* __restrict__ partial,
                                                int* __restrict__ off,
                                                int* __restrict__ cursor) {
    int i = blockIdx.x * SCAN_B + threadIdx.x;
    int v = (i < NN) ? cnt[i] : 0;
    const int lane = threadIdx.x & 63, wid = threadIdx.x >> 6;
    int s = v;
#pragma unroll
    for (int o = 1; o < 64; o <<= 1) {
        int t = __shfl_up(s, o, 64);
        if (lane >= o) s += t;
    }
    __shared__ int wsum[SCAN_B / 64];
    if (lane == 63) wsum[wid] = s;
    __syncthreads();
    int base = 0;
    for (int w = 0; w < wid; ++w) base += wsum[w];
    const int excl = partial[blockIdx.x] + base + s - v;
    if (i < NN) {
        off[i]    = excl;
        cursor[i] = excl;
        if (i == NN - 1) off[NN] = excl + v;
    }
}

// ---------------- counting-sort scatter of (src, weight) ----------------
__global__ __launch_bounds__(256) void scatter_sort(const int* __restrict__ esrc,
                                                    const int* __restrict__ edst,
                                                    const float* __restrict__ ew,
                                                    int* __restrict__ cursor,
                                                    int2* __restrict__ pairs) {
    int i = blockIdx.x * blockDim.x + threadIdx.x;
    const int stride = gridDim.x * blockDim.x;
    for (int e = i; e < NE; e += stride) {
        const int d   = edst[e];
        const int pos = atomicAdd(&cursor[d], 1);
        int2 p;
        p.x = esrc[e];
        p.y = __float_as_int(ew[e]);
        pairs[pos] = p;
    }
}

// ---------------- fused gather + epilogue ----------------
// wave per dst row: sum in-edges (x[src]*w) in registers, then
// support = 0.9*hi + 0.1*h0 ; out = theta*(support@W) + (1-theta)*support + x
__global__ __launch_bounds__(256) void gather_fused(const int* __restrict__ off,
                                                    const int2* __restrict__ pairs,
                                                    const float* __restrict__ x,
                                                    const float* __restrict__ h0,
                                                    const float* __restrict__ W,
                                                    const int* __restrict__ lp,
                                                    float* __restrict__ out) {
    const int lane   = threadIdx.x & 63;
    int       wave   = (blockIdx.x * blockDim.x + threadIdx.x) >> 6;
    const int nwaves = (gridDim.x * blockDim.x) >> 6;

    const float theta = logf(0.5f / (float)lp[0] + 1.0f);
    const float omt   = 1.0f - theta;

    // column `lane` of W (coalesced across lanes), kept in 64 VGPRs
    float wcol[64];
#pragma unroll
    for (int k = 0; k < 64; ++k) wcol[k] = W[k * DD + lane];

    for (int row = wave; row < NN; row += nwaves) {
        const int b = off[row];
        const int e = off[row + 1];

        float acc = 0.f;
        for (int c = b; c < e; c += 64) {
            const int m = min(64, e - c);
            int2 p = (c + lane < e) ? pairs[c + lane] : make_int2(0, 0);
            int k = 0;
            // 4-wide ILP: 4 independent x-row loads in flight
            for (; k + 4 <= m; k += 4) {
                const int   s0 = __shfl(p.x, k, 64),  s1 = __shfl(p.x, k + 1, 64);
                const int   s2 = __shfl(p.x, k + 2, 64), s3 = __shfl(p.x, k + 3, 64);
                const float w0 = __shfl(__int_as_float(p.y), k, 64);
                const float w1 = __shfl(__int_as_float(p.y), k + 1, 64);
                const float w2 = __shfl(__int_as_float(p.y), k + 2, 64);
                const float w3 = __shfl(__int_as_float(p.y), k + 3, 64);
                const float x0 = x[s0 * DD + lane];
                const float x1 = x[s1 * DD + lane];
                const float x2 = x[s2 * DD + lane];
                const float x3 = x[s3 * DD + lane];
                acc = fmaf(x0, w0, acc);
                acc = fmaf(x1, w1, acc);
                acc = fmaf(x2, w2, acc);
                acc = fmaf(x3, w3, acc);
            }
            for (; k < m; ++k) {
                const int   s  = __shfl(p.x, k, 64);
                const float wk = __shfl(__int_as_float(p.y), k, 64);
                acc = fmaf(x[s * DD + lane], wk, acc);
            }
        }

        const float sv = fmaf(0.9f, acc, 0.1f * h0[row * DD + lane]);
        float macc = 0.f;
#pragma unroll
        for (int k = 0; k < 64; ++k)
            macc = fmaf(__shfl(sv, k, 64), wcol[k], macc);
        out[row * DD + lane] = fmaf(theta, macc, omt * sv) + x[row * DD + lane];
    }
}

extern "C" void kernel_launch(void* const* d_in, const int* in_sizes, int n_in,
                              void* d_out, int out_size, void* d_ws, size_t ws_size,
                              hipStream_t stream) {
    const float* x    = (const float*)d_in[0];   // [NN, 64]
    const float* h0   = (const float*)d_in[1];   // [NN, 64]
    const int*   esrc = (const int*)  d_in[2];   // [NE]
    const int*   edst = (const int*)  d_in[3];   // [NE]
    const float* ew   = (const float*)d_in[4];   // [NE]
    const float* W    = (const float*)d_in[5];   // [64, 64]
    const int*   lp   = (const int*)  d_in[6];   // scalar l
    float*       out  = (float*)d_out;

    // ---- workspace layout (bytes) ----
    char* ws = (char*)d_ws;
    int*  cnt     = (int*) (ws + 0);              //  400000 B
    int*  off     = (int*) (ws + 400000);         //  400004 B -> pad to 800016
    int*  cursor  = (int*) (ws + 800016);         //  400000 B
    int*  partial = (int*) (ws + 1200016);        //     392 B -> pad to 1200416
    int2* pairs   = (int2*)(ws + 1200416);        // 12.8 MB  -> end ~14.0 MB

    zero_cnt<<<(NN + 255) / 256, 256, 0, stream>>>(cnt);
    hist<<<2048, 256, 0, stream>>>(edst, cnt);
    scan1<<<SCAN_NB, SCAN_B, 0, stream>>>(cnt, partial);
    scan2<<<1, 64, 0, stream>>>(partial);
    scan3<<<SCAN_NB, SCAN_B, 0, stream>>>(cnt, partial, off, cursor);
    scatter_sort<<<2048, 256, 0, stream>>>(esrc, edst, ew, cursor, pairs);
    gather_fused<<<2048, 256, 0, stream>>>(off, pairs, x, h0, W, lp, out);
}

// Round 4
// 483.185 us; speedup vs baseline: 1.0661x; 1.0338x over previous
//
#include <hip/hip_runtime.h>
#include <math.h>

#define NN 100000
#define NE 1600000
#define DD 64

#define SCAN_B 1024
#define SCAN_NB ((NN + SCAN_B - 1) / SCAN_B)   // 98 blocks

// ---------------- dense pre-pass ----------------
// M = theta*W + (1-theta)*I
// y = x@M            (gather operand)
// out = z = 0.1*h0@M + x   (epilogue baseline, gather adds 0.9*A@y)
__global__ __launch_bounds__(256) void dense_pre(const float* __restrict__ x,
                                                 const float* __restrict__ h0,
                                                 const float* __restrict__ W,
                                                 const int*   __restrict__ lp,
                                                 float* __restrict__ y,
                                                 float* __restrict__ out) {
    __shared__ float Wl[DD * DD];
    for (int i = threadIdx.x; i < DD * DD; i += blockDim.x) Wl[i] = W[i];
    __syncthreads();

    const int lane   = threadIdx.x & 63;
    int       wave   = (blockIdx.x * blockDim.x + threadIdx.x) >> 6;
    const int nwaves = (gridDim.x * blockDim.x) >> 6;

    const float theta = logf(0.5f / (float)lp[0] + 1.0f);
    const float omt   = 1.0f - theta;

    for (int row = wave; row < NN; row += nwaves) {
        const float sx = x[row * DD + lane];
        const float sh = h0[row * DD + lane];
        float ax = 0.f, ah = 0.f;
#pragma unroll
        for (int k = 0; k < DD; ++k) {
            const float wk = Wl[k * DD + lane];   // 2-way bank alias: free
            ax = fmaf(__shfl(sx, k, 64), wk, ax);
            ah = fmaf(__shfl(sh, k, 64), wk, ah);
        }
        const float yv = fmaf(theta, ax, omt * sx);
        const float zv = fmaf(0.1f, fmaf(theta, ah, omt * sh), sx);
        y[row * DD + lane]   = yv;
        out[row * DD + lane] = zv;
    }
}

// ---------------- histogram of dst degrees (4 edges/thread) ----------------
__global__ __launch_bounds__(256) void hist(const int4* __restrict__ edst4,
                                            int* __restrict__ cnt) {
    int i = blockIdx.x * blockDim.x + threadIdx.x;
    const int stride = gridDim.x * blockDim.x;
    for (int e = i; e < NE / 4; e += stride) {
        const int4 d = edst4[e];
        atomicAdd(&cnt[d.x], 1);
        atomicAdd(&cnt[d.y], 1);
        atomicAdd(&cnt[d.z], 1);
        atomicAdd(&cnt[d.w], 1);
    }
}

// ---------------- scan step 1: per-block sums ----------------
__global__ __launch_bounds__(SCAN_B) void scan1(const int* __restrict__ cnt,
                                                int* __restrict__ partial) {
    int i = blockIdx.x * SCAN_B + threadIdx.x;
    int v = (i < NN) ? cnt[i] : 0;
#pragma unroll
    for (int o = 1; o < 64; o <<= 1) v += __shfl_xor(v, o, 64);
    __shared__ int wsum[SCAN_B / 64];
    const int wid = threadIdx.x >> 6, lane = threadIdx.x & 63;
    if (lane == 0) wsum[wid] = v;
    __syncthreads();
    if (threadIdx.x == 0) {
        int s = 0;
#pragma unroll
        for (int w = 0; w < SCAN_B / 64; ++w) s += wsum[w];
        partial[blockIdx.x] = s;
    }
}

// ---------------- scan step 2: one-wave shfl exclusive scan ----------------
__global__ void scan2(int* __restrict__ partial) {
    const int lane = threadIdx.x;   // 64 threads
    int base = 0;
    for (int start = 0; start < SCAN_NB; start += 64) {
        const int i = start + lane;
        int v = (i < SCAN_NB) ? partial[i] : 0;
        int s = v;
#pragma unroll
        for (int o = 1; o < 64; o <<= 1) {
            int t = __shfl_up(s, o, 64);
            if (lane >= o) s += t;
        }
        if (i < SCAN_NB) partial[i] = base + s - v;
        base += __shfl(s, 63, 64);
    }
}

// ---------------- scan step 3: exclusive offsets + cursor copy ----------------
__global__ __launch_bounds__(SCAN_B) void scan3(const int* __restrict__ cnt,
                                                const int* __restrict__ partial,
                                                int* __restrict__ off,
                                                int* __restrict__ cursor) {
    int i = blockIdx.x * SCAN_B + threadIdx.x;
    int v = (i < NN) ? cnt[i] : 0;
    const int lane = threadIdx.x & 63, wid = threadIdx.x >> 6;
    int s = v;
#pragma unroll
    for (int o = 1; o < 64; o <<= 1) {
        int t = __shfl_up(s, o, 64);
        if (lane >= o) s += t;
    }
    __shared__ int wsum[SCAN_B / 64];
    if (lane == 63) wsum[wid] = s;
    __syncthreads();
    int base = 0;
    for (int w = 0; w < wid; ++w) base += wsum[w];
    const int excl = partial[blockIdx.x] + base + s - v;
    if (i < NN) {
        off[i]    = excl;
        cursor[i] = excl;
        if (i == NN - 1) off[NN] = excl + v;
    }
}

// ---------------- counting-sort scatter of (src, weight), 4 edges/thread ----
__global__ __launch_bounds__(256) void scatter_sort(const int4* __restrict__ esrc4,
                                                    const int4* __restrict__ edst4,
                                                    const float4* __restrict__ ew4,
                                                    int* __restrict__ cursor,
                                                    int2* __restrict__ pairs) {
    int i = blockIdx.x * blockDim.x + threadIdx.x;
    const int stride = gridDim.x * blockDim.x;
    for (int e = i; e < NE / 4; e += stride) {
        const int4   s = esrc4[e];
        const int4   d = edst4[e];
        const float4 w = ew4[e];
        int p;
        p = atomicAdd(&cursor[d.x], 1); pairs[p] = make_int2(s.x, __float_as_int(w.x));
        p = atomicAdd(&cursor[d.y], 1); pairs[p] = make_int2(s.y, __float_as_int(w.y));
        p = atomicAdd(&cursor[d.z], 1); pairs[p] = make_int2(s.z, __float_as_int(w.z));
        p = atomicAdd(&cursor[d.w], 1); pairs[p] = make_int2(s.w, __float_as_int(w.w));
    }
}

// ---------------- gather: out[row] += 0.9 * sum_e w_e * y[src_e] ----------------
// wave per dst row, lane = feature; low-VGPR so 8 waves/SIMD fit.
__global__ __launch_bounds__(256, 8) void gather_axpy(const int* __restrict__ off,
                                                      const int2* __restrict__ pairs,
                                                      const float* __restrict__ y,
                                                      float* __restrict__ out) {
    const int lane   = threadIdx.x & 63;
    int       wave   = (blockIdx.x * blockDim.x + threadIdx.x) >> 6;
    const int nwaves = (gridDim.x * blockDim.x) >> 6;

    for (int row = wave; row < NN; row += nwaves) {
        const int b = off[row];
        const int e = off[row + 1];

        float acc = 0.f;
        for (int c = b; c < e; c += 64) {
            const int m = min(64, e - c);
            int2 p = (c + lane < e) ? pairs[c + lane] : make_int2(0, 0);
            int k = 0;
            for (; k + 4 <= m; k += 4) {
                const int   s0 = __shfl(p.x, k, 64),     s1 = __shfl(p.x, k + 1, 64);
                const int   s2 = __shfl(p.x, k + 2, 64), s3 = __shfl(p.x, k + 3, 64);
                const float w0 = __shfl(__int_as_float(p.y), k, 64);
                const float w1 = __shfl(__int_as_float(p.y), k + 1, 64);
                const float w2 = __shfl(__int_as_float(p.y), k + 2, 64);
                const float w3 = __shfl(__int_as_float(p.y), k + 3, 64);
                const float x0 = y[s0 * DD + lane];
                const float x1 = y[s1 * DD + lane];
                const float x2 = y[s2 * DD + lane];
                const float x3 = y[s3 * DD + lane];
                acc = fmaf(x0, w0, acc);
                acc = fmaf(x1, w1, acc);
                acc = fmaf(x2, w2, acc);
                acc = fmaf(x3, w3, acc);
            }
            for (; k < m; ++k) {
                const int   s  = __shfl(p.x, k, 64);
                const float wk = __shfl(__int_as_float(p.y), k, 64);
                acc = fmaf(y[s * DD + lane], wk, acc);
            }
        }

        const int idx = row * DD + lane;
        out[idx] = fmaf(0.9f, acc, out[idx]);
    }
}

extern "C" void kernel_launch(void* const* d_in, const int* in_sizes, int n_in,
                              void* d_out, int out_size, void* d_ws, size_t ws_size,
                              hipStream_t stream) {
    const float* x    = (const float*)d_in[0];   // [NN, 64]
    const float* h0   = (const float*)d_in[1];   // [NN, 64]
    const int*   esrc = (const int*)  d_in[2];   // [NE]
    const int*   edst = (const int*)  d_in[3];   // [NE]
    const float* ew   = (const float*)d_in[4];   // [NE]
    const float* W    = (const float*)d_in[5];   // [64, 64]
    const int*   lp   = (const int*)  d_in[6];   // scalar l
    float*       out  = (float*)d_out;

    // ---- workspace layout (bytes) ----
    char* ws = (char*)d_ws;
    float* y      = (float*)(ws + 0);             // 25,600,000 B
    int*   cnt    = (int*)  (ws + 25600000);      //    400,000 B
    int*   off    = (int*)  (ws + 26000000);      //    400,004 B -> pad to 26400016
    int*   cursor = (int*)  (ws + 26400016);      //    400,000 B
    int*   partial= (int*)  (ws + 26800016);      //        392 B -> pad to 26800416
    int2*  pairs  = (int2*) (ws + 26800416);      // 12,800,000 B -> end ~39.6 MB

    hipMemsetAsync(cnt, 0, NN * sizeof(int), stream);
    dense_pre<<<1024, 256, 0, stream>>>(x, h0, W, lp, y, out);
    hist<<<1024, 256, 0, stream>>>((const int4*)edst, cnt);
    scan1<<<SCAN_NB, SCAN_B, 0, stream>>>(cnt, partial);
    scan2<<<1, 64, 0, stream>>>(partial);
    scan3<<<SCAN_NB, SCAN_B, 0, stream>>>(cnt, partial, off, cursor);
    scatter_sort<<<1024, 256, 0, stream>>>((const int4*)esrc, (const int4*)edst,
                                           (const float4*)ew, cursor, pairs);
    gather_axpy<<<2048, 256, 0, stream>>>(off, pairs, y, out);
}

// Round 13
// 382.701 us; speedup vs baseline: 1.3460x; 1.2626x over previous
//
#include <hip/hip_runtime.h>
#include <math.h>

#define NN 100000
#define NE 1600000
#define DD 64

#define SCAN_B 1024
#define SCAN_NB ((NN + SCAN_B - 1) / SCAN_B)   // 98 blocks

// ---------------- histogram of dst degrees (4 edges/thread) ----------------
__global__ __launch_bounds__(256) void hist(const int4* __restrict__ edst4,
                                            int* __restrict__ cnt) {
    int i = blockIdx.x * blockDim.x + threadIdx.x;
    const int stride = gridDim.x * blockDim.x;
    for (int e = i; e < NE / 4; e += stride) {
        const int4 d = edst4[e];
        atomicAdd(&cnt[d.x], 1);
        atomicAdd(&cnt[d.y], 1);
        atomicAdd(&cnt[d.z], 1);
        atomicAdd(&cnt[d.w], 1);
    }
}

// ---------------- scan step 1: per-block sums ----------------
__global__ __launch_bounds__(SCAN_B) void scan1(const int* __restrict__ cnt,
                                                int* __restrict__ partial) {
    int i = blockIdx.x * SCAN_B + threadIdx.x;
    int v = (i < NN) ? cnt[i] : 0;
#pragma unroll
    for (int o = 1; o < 64; o <<= 1) v += __shfl_xor(v, o, 64);
    __shared__ int wsum[SCAN_B / 64];
    const int wid = threadIdx.x >> 6, lane = threadIdx.x & 63;
    if (lane == 0) wsum[wid] = v;
    __syncthreads();
    if (threadIdx.x == 0) {
        int s = 0;
#pragma unroll
        for (int w = 0; w < SCAN_B / 64; ++w) s += wsum[w];
        partial[blockIdx.x] = s;
    }
}

// ---------------- scan step 2: one-wave shfl exclusive scan ----------------
__global__ void scan2(int* __restrict__ partial) {
    const int lane = threadIdx.x;   // 64 threads
    int base = 0;
    for (int start = 0; start < SCAN_NB; start += 64) {
        const int i = start + lane;
        int v = (i < SCAN_NB) ? partial[i] : 0;
        int s = v;
#pragma unroll
        for (int o = 1; o < 64; o <<= 1) {
            int t = __shfl_up(s, o, 64);
            if (lane >= o) s += t;
        }
        if (i < SCAN_NB) partial[i] = base + s - v;
        base += __shfl(s, 63, 64);
    }
}

// ---------------- scan step 3: exclusive offsets + cursor copy ----------------
__global__ __launch_bounds__(SCAN_B) void scan3(const int* __restrict__ cnt,
                                                const int* __restrict__ partial,
                                                int* __restrict__ off,
                                                int* __restrict__ cursor) {
    int i = blockIdx.x * SCAN_B + threadIdx.x;
    int v = (i < NN) ? cnt[i] : 0;
    const int lane = threadIdx.x & 63, wid = threadIdx.x >> 6;
    int s = v;
#pragma unroll
    for (int o = 1; o < 64; o <<= 1) {
        int t = __shfl_up(s, o, 64);
        if (lane >= o) s += t;
    }
    __shared__ int wsum[SCAN_B / 64];
    if (lane == 63) wsum[wid] = s;
    __syncthreads();
    int base = 0;
    for (int w = 0; w < wid; ++w) base += wsum[w];
    const int excl = partial[blockIdx.x] + base + s - v;
    if (i < NN) {
        off[i]    = excl;
        cursor[i] = excl;
        if (i == NN - 1) off[NN] = excl + v;
    }
}

// ---------------- counting-sort scatter of (src, weight), 4 edges/thread ----
__global__ __launch_bounds__(256) void scatter_sort(const int4* __restrict__ esrc4,
                                                    const int4* __restrict__ edst4,
                                                    const float4* __restrict__ ew4,
                                                    int* __restrict__ cursor,
                                                    int2* __restrict__ pairs) {
    int i = blockIdx.x * blockDim.x + threadIdx.x;
    const int stride = gridDim.x * blockDim.x;
    for (int e = i; e < NE / 4; e += stride) {
        const int4   s = esrc4[e];
        const int4   d = edst4[e];
        const float4 w = ew4[e];
        int p;
        p = atomicAdd(&cursor[d.x], 1); pairs[p] = make_int2(s.x, __float_as_int(w.x));
        p = atomicAdd(&cursor[d.y], 1); pairs[p] = make_int2(s.y, __float_as_int(w.y));
        p = atomicAdd(&cursor[d.z], 1); pairs[p] = make_int2(s.z, __float_as_int(w.z));
        p = atomicAdd(&cursor[d.w], 1); pairs[p] = make_int2(s.w, __float_as_int(w.w));
    }
}

// ---------------- raw gather: hi[row] = sum_e w_e * x[src_e] ----------------
// wave per dst row, lane = feature; low-VGPR so 8 waves/SIMD fit.
__global__ __launch_bounds__(256, 8) void gather_raw(const int* __restrict__ off,
                                                     const int2* __restrict__ pairs,
                                                     const float* __restrict__ x,
                                                     float* __restrict__ hi) {
    const int lane   = threadIdx.x & 63;
    int       wave   = (blockIdx.x * blockDim.x + threadIdx.x) >> 6;
    const int nwaves = (gridDim.x * blockDim.x) >> 6;

    for (int row = wave; row < NN; row += nwaves) {
        const int b = off[row];
        const int e = off[row + 1];

        float acc = 0.f;
        for (int c = b; c < e; c += 64) {
            const int m = min(64, e - c);
            int2 p = (c + lane < e) ? pairs[c + lane] : make_int2(0, 0);
            int k = 0;
            for (; k + 4 <= m; k += 4) {
                const int   s0 = __shfl(p.x, k, 64),     s1 = __shfl(p.x, k + 1, 64);
                const int   s2 = __shfl(p.x, k + 2, 64), s3 = __shfl(p.x, k + 3, 64);
                const float w0 = __shfl(__int_as_float(p.y), k, 64);
                const float w1 = __shfl(__int_as_float(p.y), k + 1, 64);
                const float w2 = __shfl(__int_as_float(p.y), k + 2, 64);
                const float w3 = __shfl(__int_as_float(p.y), k + 3, 64);
                const float x0 = x[s0 * DD + lane];
                const float x1 = x[s1 * DD + lane];
                const float x2 = x[s2 * DD + lane];
                const float x3 = x[s3 * DD + lane];
                acc = fmaf(x0, w0, acc);
                acc = fmaf(x1, w1, acc);
                acc = fmaf(x2, w2, acc);
                acc = fmaf(x3, w3, acc);
            }
            for (; k < m; ++k) {
                const int   s  = __shfl(p.x, k, 64);
                const float wk = __shfl(__int_as_float(p.y), k, 64);
                acc = fmaf(x[s * DD + lane], wk, acc);
            }
        }
        hi[row * DD + lane] = acc;
    }
}

// ---------------- dense post-pass: block-tile GEMM, no shfl, no asm ----------
// support = 0.9*hi + 0.1*h0
// out     = theta*(support@W) + (1-theta)*support + x
// Block owns 256 rows; thread owns one row; support tile staged in LDS
// (stride 33 -> (lane+k)%32 conflict-free b32 reads); W[k][j] is wave-uniform
// -> compiler emits s_load (scalar-pipe broadcast); 64 static accumulators.
#define TB 256
#define TKC 32
__global__ __launch_bounds__(256) void dense_post(const float* __restrict__ hi,
                                                  const float* __restrict__ h0,
                                                  const float* __restrict__ x,
                                                  const float* __restrict__ W,
                                                  const int*   __restrict__ lp,
                                                  float* __restrict__ out) {
    __shared__ float buf[TB * 33];          // 33.8 KB
    const int t    = threadIdx.x;           // owns row base+t
    const int base = blockIdx.x * TB;

    const float theta = logf(0.5f / (float)lp[0] + 1.0f);
    const float omt   = 1.0f - theta;

    float acc[DD];
#pragma unroll
    for (int j = 0; j < DD; ++j) acc[j] = 0.f;

    for (int kc = 0; kc < DD; kc += TKC) {
        __syncthreads();                    // buf reuse vs previous reads
        // stage support[base..base+255][kc..kc+31]; coalesced float4 loads,
        // b32 LDS writes (stride 33 keeps banks conflict-free, 4B-aligned)
#pragma unroll
        for (int it = 0; it < 8; ++it) {
            const int idx = it * 256 + t;   // 0..2047
            const int r = idx >> 3, f4 = idx & 7;
            const int gr = base + r;
            float4 v = make_float4(0.f, 0.f, 0.f, 0.f);
            if (gr < NN) {
                const float4 a = *(const float4*)&hi[gr * DD + kc + 4 * f4];
                const float4 b = *(const float4*)&h0[gr * DD + kc + 4 * f4];
                v.x = fmaf(0.9f, a.x, 0.1f * b.x);
                v.y = fmaf(0.9f, a.y, 0.1f * b.y);
                v.z = fmaf(0.9f, a.z, 0.1f * b.z);
                v.w = fmaf(0.9f, a.w, 0.1f * b.w);
            }
            const int lb = r * 33 + 4 * f4;
            buf[lb]     = v.x;
            buf[lb + 1] = v.y;
            buf[lb + 2] = v.z;
            buf[lb + 3] = v.w;
        }
        __syncthreads();
        // compute: acc[j] += support[row][k] * W[k][j]
        for (int k = 0; k < TKC; ++k) {
            const float sk = buf[t * 33 + k];
            const float* wrow = &W[(kc + k) * DD];
#pragma unroll
            for (int j = 0; j < DD; ++j)
                acc[j] = fmaf(sk, wrow[j], acc[j]);
        }
    }

    // transpose acc through LDS in j-chunks of 32 for coalesced stores,
    // fusing the epilogue (support reload is L2-hot and coalesced).
    for (int jc = 0; jc < DD; jc += 32) {
        __syncthreads();
#pragma unroll
        for (int jj = 0; jj < 32; ++jj) buf[t * 33 + jj] = acc[jc + jj];
        __syncthreads();
#pragma unroll
        for (int it = 0; it < 8; ++it) {
            const int idx = it * 256 + t;
            const int r = idx >> 3, f4 = idx & 7;
            const int gr = base + r;
            if (gr < NN) {
                const int lb  = r * 33 + 4 * f4;
                const int col = jc + 4 * f4;
                const float4 a  = *(const float4*)&hi[gr * DD + col];
                const float4 b  = *(const float4*)&h0[gr * DD + col];
                const float4 xx = *(const float4*)&x[gr * DD + col];
                float4 o;
                const float s0 = fmaf(0.9f, a.x, 0.1f * b.x);
                const float s1 = fmaf(0.9f, a.y, 0.1f * b.y);
                const float s2 = fmaf(0.9f, a.z, 0.1f * b.z);
                const float s3 = fmaf(0.9f, a.w, 0.1f * b.w);
                o.x = fmaf(theta, buf[lb],     fmaf(omt, s0, xx.x));
                o.y = fmaf(theta, buf[lb + 1], fmaf(omt, s1, xx.y));
                o.z = fmaf(theta, buf[lb + 2], fmaf(omt, s2, xx.z));
                o.w = fmaf(theta, buf[lb + 3], fmaf(omt, s3, xx.w));
                *(float4*)&out[gr * DD + col] = o;
            }
        }
    }
}

extern "C" void kernel_launch(void* const* d_in, const int* in_sizes, int n_in,
                              void* d_out, int out_size, void* d_ws, size_t ws_size,
                              hipStream_t stream) {
    const float* x    = (const float*)d_in[0];   // [NN, 64]
    const float* h0   = (const float*)d_in[1];   // [NN, 64]
    const int*   esrc = (const int*)  d_in[2];   // [NE]
    const int*   edst = (const int*)  d_in[3];   // [NE]
    const float* ew   = (const float*)d_in[4];   // [NE]
    const float* W    = (const float*)d_in[5];   // [64, 64]
    const int*   lp   = (const int*)  d_in[6];   // scalar l
    float*       out  = (float*)d_out;

    // ---- workspace layout (bytes) ----
    char* ws = (char*)d_ws;
    float* hi     = (float*)(ws + 0);             // 25,600,000 B
    int*   cnt    = (int*)  (ws + 25600000);      //    400,000 B
    int*   off    = (int*)  (ws + 26000000);      //    400,004 B -> pad to 26400016
    int*   cursor = (int*)  (ws + 26400016);      //    400,000 B
    int*   partial= (int*)  (ws + 26800016);      //        392 B -> pad to 26800416
    int2*  pairs  = (int2*) (ws + 26800416);      // 12,800,000 B -> end ~39.6 MB

    hipMemsetAsync(cnt, 0, NN * sizeof(int), stream);
    hist<<<1024, 256, 0, stream>>>((const int4*)edst, cnt);
    scan1<<<SCAN_NB, SCAN_B, 0, stream>>>(cnt, partial);
    scan2<<<1, 64, 0, stream>>>(partial);
    scan3<<<SCAN_NB, SCAN_B, 0, stream>>>(cnt, partial, off, cursor);
    scatter_sort<<<1024, 256, 0, stream>>>((const int4*)esrc, (const int4*)edst,
                                           (const float4*)ew, cursor, pairs);
    gather_raw<<<2048, 256, 0, stream>>>(off, pairs, x, hi);
    dense_post<<<(NN + TB - 1) / TB, TB, 0, stream>>>(hi, h0, x, W, lp, out);
}